// Round 1
// baseline (5668.994 us; speedup 1.0000x reference)
//
#include <hip/hip_runtime.h>
#include <hip/hip_bf16.h>
#include <math.h>

#define D_MODEL 1024
#define NHEADS  16
#define DK      64
#define SEQ     2048
#define BATCH   2

// C[M,N] = A[M,K] @ B[N,K]^T (+ bias[N]).  A,B,C row-major.
// 64x64 tile, BK=16, 256 threads, 4x4 register blocking.
__global__ __launch_bounds__(256) void gemm_abt(const float* __restrict__ A,
                                                const float* __restrict__ B,
                                                const float* __restrict__ bias,
                                                float* __restrict__ C,
                                                int M, int N, int K) {
    __shared__ __align__(16) float As[64][20];
    __shared__ __align__(16) float Bs[64][20];
    const int tid  = threadIdx.x;
    const int tx   = tid & 15;        // output col group
    const int ty   = tid >> 4;        // output row group
    const int brow = blockIdx.y * 64;
    const int bcol = blockIdx.x * 64;
    const int lrow = tid >> 2;        // loader row 0..63
    const int lcol = (tid & 3) * 4;   // loader col 0,4,8,12

    float acc[4][4] = {};

    for (int k0 = 0; k0 < K; k0 += 16) {
        float4 av = *(const float4*)&A[(size_t)(brow + lrow) * K + k0 + lcol];
        float4 bv = *(const float4*)&B[(size_t)(bcol + lrow) * K + k0 + lcol];
        *(float4*)&As[lrow][lcol] = av;
        *(float4*)&Bs[lrow][lcol] = bv;
        __syncthreads();
#pragma unroll
        for (int kk = 0; kk < 16; ++kk) {
            float a[4], b[4];
#pragma unroll
            for (int i = 0; i < 4; ++i) a[i] = As[ty * 4 + i][kk];
#pragma unroll
            for (int j = 0; j < 4; ++j) b[j] = Bs[tx * 4 + j][kk];
#pragma unroll
            for (int i = 0; i < 4; ++i)
#pragma unroll
                for (int j = 0; j < 4; ++j) acc[i][j] += a[i] * b[j];
        }
        __syncthreads();
    }

#pragma unroll
    for (int i = 0; i < 4; ++i) {
        const int row = brow + ty * 4 + i;
#pragma unroll
        for (int j = 0; j < 4; ++j) {
            const int col = bcol + tx * 4 + j;
            float v = acc[i][j];
            if (bias) v += bias[col];
            C[(size_t)row * N + col] = v;
        }
    }
}

// In-place interleaved RoPE on the q and k slices of qkv [B,S,3D].
// One thread per (b,s,part,h,pair).
__global__ __launch_bounds__(256) void rope_kernel(float* __restrict__ qkv) {
    const int tid = blockIdx.x * blockDim.x + threadIdx.x;
    const int NP  = DK / 2;                     // 32 pairs per head
    const int i    = tid & (NP - 1);            // pair index
    const int h    = (tid >> 5) & (NHEADS - 1); // head
    const int part = (tid >> 9) & 1;            // 0=q, 1=k
    const int s    = (tid >> 10) & (SEQ - 1);   // position
    const int b    = tid >> 21;                 // batch
    if (b >= BATCH) return;

    const size_t base = ((size_t)(b * SEQ + s)) * (3 * D_MODEL)
                      + (size_t)part * D_MODEL + h * DK + 2 * i;
    const float x0 = qkv[base];
    const float x1 = qkv[base + 1];
    // inv_freq = 50^(-(2i)/64)
    const float inv_freq = exp2f(-(2.0f * (float)i / (float)DK) * log2f(50.0f));
    const float angle = (float)s * inv_freq;
    float sn, cs;
    __sincosf(angle, &sn, &cs);
    qkv[base]     = x0 * cs - x1 * sn;
    qkv[base + 1] = x1 * cs + x0 * sn;
}

// Attention: one block (256 threads) per (b,h,q) row.
// Phase 1: each thread computes 8 scores, block max.
// Phase 2: exp/sum -> probs in LDS.
// Phase 3: lane=dim coalesced PV accumulation, 4 key-chunks reduced via LDS.
__global__ __launch_bounds__(256) void attn_kernel(const float* __restrict__ qkv,
                                                   float* __restrict__ out) {
    const int q_idx = blockIdx.x;
    const int h     = blockIdx.y;
    const int b     = blockIdx.z;
    const int tid   = threadIdx.x;
    const int wave  = tid >> 6;
    const int lane  = tid & 63;

    __shared__ __align__(16) float q_sh[DK];
    __shared__ float probs[SEQ];
    __shared__ float red[4];
    __shared__ float redv[4][DK];
    __shared__ float m_sh, l_sh;

    const size_t row_stride = 3 * D_MODEL;
    const float* qrow = qkv + ((size_t)(b * SEQ + q_idx)) * row_stride + h * DK;
    if (tid < DK) q_sh[tid] = qrow[tid];
    __syncthreads();

    // ---- Phase 1: scores + local max ----
    float sc[8];
    float lmax = -1e30f;
#pragma unroll
    for (int j = 0; j < 8; ++j) {
        const int t = tid + j * 256;
        const float4* krow = (const float4*)(qkv + ((size_t)(b * SEQ + t)) * row_stride
                                             + D_MODEL + h * DK);
        float dot = 0.f;
#pragma unroll
        for (int c = 0; c < 16; ++c) {
            const float4 kv = krow[c];
            const float4 qv = ((const float4*)q_sh)[c];
            dot += kv.x * qv.x + kv.y * qv.y + kv.z * qv.z + kv.w * qv.w;
        }
        float s = dot * 0.125f;           // 1/sqrt(64)
        if (t == q_idx) s = -1e30f;       // diagonal mask
        sc[j] = s;
        lmax = fmaxf(lmax, s);
    }
    // block max
#pragma unroll
    for (int off = 32; off >= 1; off >>= 1)
        lmax = fmaxf(lmax, __shfl_xor(lmax, off, 64));
    if (lane == 0) red[wave] = lmax;
    __syncthreads();
    if (tid == 0) m_sh = fmaxf(fmaxf(red[0], red[1]), fmaxf(red[2], red[3]));
    __syncthreads();
    const float m = m_sh;

    // ---- Phase 2: exp + sum ----
    float lsum = 0.f;
#pragma unroll
    for (int j = 0; j < 8; ++j) {
        const int t = tid + j * 256;
        const float p = expf(sc[j] - m);
        probs[t] = p;
        lsum += p;
    }
#pragma unroll
    for (int off = 32; off >= 1; off >>= 1)
        lsum += __shfl_xor(lsum, off, 64);
    if (lane == 0) red[wave] = lsum;
    __syncthreads();
    if (tid == 0) l_sh = red[0] + red[1] + red[2] + red[3];
    __syncthreads();
    const float inv_l = 1.0f / l_sh;

    // ---- Phase 3: PV.  lane -> dim (coalesced), wave -> key chunk ----
    const int d = lane;
    const int c = wave;
    const float* vbase = qkv + (size_t)b * SEQ * row_stride + 2 * D_MODEL + h * DK + d;
    float partial = 0.f;
    const int t0 = c * (SEQ / 4);
#pragma unroll 4
    for (int t = t0; t < t0 + SEQ / 4; ++t) {
        partial += probs[t] * vbase[(size_t)t * row_stride];
    }
    redv[c][d] = partial;
    __syncthreads();
    if (tid < DK) {
        const float r = (redv[0][tid] + redv[1][tid] + redv[2][tid] + redv[3][tid]) * inv_l;
        out[((size_t)(b * SEQ + q_idx)) * D_MODEL + h * DK + tid] = r;
    }
}

extern "C" void kernel_launch(void* const* d_in, const int* in_sizes, int n_in,
                              void* d_out, int out_size, void* d_ws, size_t ws_size,
                              hipStream_t stream) {
    const float* x     = (const float*)d_in[0];   // [B,S,D]
    const float* w_qkv = (const float*)d_in[1];   // [3D,D]
    const float* w_out = (const float*)d_in[2];   // [D,D]
    const float* b_out = (const float*)d_in[3];   // [D]
    float* out = (float*)d_out;                   // [B,S,D]

    float* qkv      = (float*)d_ws;                                   // [B,S,3D] = 50.3 MB
    float* attn_out = qkv + (size_t)BATCH * SEQ * 3 * D_MODEL;        // [B,S,D]  = 16.8 MB

    const int M = BATCH * SEQ;        // 4096

    // 1) qkv = x @ w_qkv^T
    {
        dim3 grid(3 * D_MODEL / 64, M / 64);
        gemm_abt<<<grid, 256, 0, stream>>>(x, w_qkv, nullptr, qkv, M, 3 * D_MODEL, D_MODEL);
    }
    // 2) RoPE in-place on q,k
    {
        const int total = BATCH * SEQ * 2 * NHEADS * (DK / 2);        // 4,194,304
        rope_kernel<<<total / 256, 256, 0, stream>>>(qkv);
    }
    // 3) attention
    {
        dim3 grid(SEQ, NHEADS, BATCH);
        attn_kernel<<<grid, 256, 0, stream>>>(qkv, attn_out);
    }
    // 4) out = attn_out @ w_out^T + b_out
    {
        dim3 grid(D_MODEL / 64, M / 64);
        gemm_abt<<<grid, 256, 0, stream>>>(attn_out, w_out, b_out, out, M, D_MODEL, D_MODEL);
    }
}

// Round 2
// 940.781 us; speedup vs baseline: 6.0258x; 6.0258x over previous
//
#include <hip/hip_runtime.h>
#include <hip/hip_bf16.h>
#include <math.h>

#define D_MODEL 1024
#define NHEADS  16
#define DK      64
#define SEQ     2048
#define BATCH   2

typedef __attribute__((ext_vector_type(8))) short  short8;
typedef __attribute__((ext_vector_type(8))) unsigned short ushort8;
typedef __attribute__((ext_vector_type(4))) float  floatx4;

__device__ __forceinline__ unsigned short f2bf(float f) {
    union { float f; unsigned int u; } v; v.f = f;
    unsigned int u = v.u;
    return (unsigned short)((u + 0x7FFFu + ((u >> 16) & 1u)) >> 16);
}

// ---------------- fp32 GEMM: C[M,N] = A[M,K] @ B[N,K]^T (+bias) ----------------
__global__ __launch_bounds__(256) void gemm_abt(const float* __restrict__ A,
                                                const float* __restrict__ B,
                                                const float* __restrict__ bias,
                                                float* __restrict__ C,
                                                int M, int N, int K) {
    __shared__ __align__(16) float As[64][20];
    __shared__ __align__(16) float Bs[64][20];
    const int tid  = threadIdx.x;
    const int tx   = tid & 15;
    const int ty   = tid >> 4;
    const int brow = blockIdx.y * 64;
    const int bcol = blockIdx.x * 64;
    const int lrow = tid >> 2;
    const int lcol = (tid & 3) * 4;

    float acc[4][4] = {};

    for (int k0 = 0; k0 < K; k0 += 16) {
        float4 av = *(const float4*)&A[(size_t)(brow + lrow) * K + k0 + lcol];
        float4 bv = *(const float4*)&B[(size_t)(bcol + lrow) * K + k0 + lcol];
        *(float4*)&As[lrow][lcol] = av;
        *(float4*)&Bs[lrow][lcol] = bv;
        __syncthreads();
#pragma unroll
        for (int kk = 0; kk < 16; ++kk) {
            float a[4], b[4];
#pragma unroll
            for (int i = 0; i < 4; ++i) a[i] = As[ty * 4 + i][kk];
#pragma unroll
            for (int j = 0; j < 4; ++j) b[j] = Bs[tx * 4 + j][kk];
#pragma unroll
            for (int i = 0; i < 4; ++i)
#pragma unroll
                for (int j = 0; j < 4; ++j) acc[i][j] += a[i] * b[j];
        }
        __syncthreads();
    }

#pragma unroll
    for (int i = 0; i < 4; ++i) {
        const int row = brow + ty * 4 + i;
#pragma unroll
        for (int j = 0; j < 4; ++j) {
            const int col = bcol + tx * 4 + j;
            float v = acc[i][j];
            if (bias) v += bias[col];
            C[(size_t)row * N + col] = v;
        }
    }
}

// ---------------- fused RoPE + bf16 pack ----------------
// qkv fp32 [B,S,3D] -> Qb [B,H,S,64] (scaled by 1/8), Kb [B,H,S,64], Vb [B,H,S,64]
__global__ __launch_bounds__(256) void rope_pack(const float* __restrict__ qkv,
                                                 unsigned short* __restrict__ Qb,
                                                 unsigned short* __restrict__ Kb,
                                                 unsigned short* __restrict__ Vb) {
    const int tid = blockIdx.x * blockDim.x + threadIdx.x;
    const int i = tid & 31;                 // pair index 0..31
    const int h = (tid >> 5) & (NHEADS - 1);
    const int s = (tid >> 9) & (SEQ - 1);
    const int b = tid >> 20;
    if (b >= BATCH) return;

    const size_t in_base = ((size_t)(b * SEQ + s)) * (3 * D_MODEL) + h * DK + 2 * i;
    const float2 q2 = *(const float2*)&qkv[in_base];
    const float2 k2 = *(const float2*)&qkv[in_base + D_MODEL];
    const float2 v2 = *(const float2*)&qkv[in_base + 2 * D_MODEL];

    const float inv_freq = exp2f(-(2.0f * (float)i / (float)DK) * log2f(50.0f));
    const float angle = (float)s * inv_freq;
    float sn, cs;
    __sincosf(angle, &sn, &cs);

    const float qr0 = q2.x * cs - q2.y * sn;
    const float qr1 = q2.y * cs + q2.x * sn;
    const float kr0 = k2.x * cs - k2.y * sn;
    const float kr1 = k2.y * cs + k2.x * sn;

    const size_t out_base = (((size_t)(b * NHEADS + h)) * SEQ + s) * DK + 2 * i;
    Qb[out_base]     = f2bf(qr0 * 0.125f);
    Qb[out_base + 1] = f2bf(qr1 * 0.125f);
    Kb[out_base]     = f2bf(kr0);
    Kb[out_base + 1] = f2bf(kr1);
    Vb[out_base]     = f2bf(v2.x);
    Vb[out_base + 1] = f2bf(v2.y);
}

// ---------------- flash attention, bf16 MFMA ----------------
// 64 queries/block, 64-key tiles, online softmax. 256 threads = 4 waves.
#define LDW 72   // 64 + 8 pad (bank-conflict-free-ish, keeps 16B alignment)

__global__ __launch_bounds__(256, 4) void flash_attn(const unsigned short* __restrict__ Qb,
                                                     const unsigned short* __restrict__ Kb,
                                                     const unsigned short* __restrict__ Vb,
                                                     float* __restrict__ attn_out) {
    const int qt   = blockIdx.x;      // query tile (of 64)
    const int h    = blockIdx.y;
    const int b    = blockIdx.z;
    const int tid  = threadIdx.x;
    const int wave = tid >> 6;
    const int lane = tid & 63;
    const int quad = lane >> 4;
    const int lcol = lane & 15;
    const int m0   = wave * 16;       // this wave's query-row stripe

    __shared__ __align__(16) unsigned short Qs[64][LDW];
    __shared__ __align__(16) unsigned short Ks[64][LDW];
    __shared__ __align__(16) unsigned short Vt[64][LDW];   // Vt[d][key]
    __shared__ __align__(16) unsigned short Ps[64][LDW];

    const size_t bh = (size_t)(b * NHEADS + h);
    const unsigned short* Qg = Qb + (bh * SEQ + (size_t)qt * 64) * DK;
    const unsigned short* Kg = Kb + bh * SEQ * DK;
    const unsigned short* Vg = Vb + bh * SEQ * DK;

    const int srow = tid >> 3;        // 0..31? no: 256/8 = 32.. need 64 rows
    // 256 threads stage a 64x64 bf16 tile: 4 rows per... use 8 threads/row over 64 rows
    const int lrow = tid >> 2;            // not used
    (void)lrow;
    const int strow = tid >> 3;           // 0..31  (two passes of 32 rows)
    const int stcol = (tid & 7) * 8;      // 0,8,...,56

    // stage Q (64 rows, two halves of 32 rows)
    *(short8*)&Qs[strow][stcol]      = *(const short8*)&Qg[(size_t)strow * DK + stcol];
    *(short8*)&Qs[strow + 32][stcol] = *(const short8*)&Qg[(size_t)(strow + 32) * DK + stcol];
    __syncthreads();

    // Q fragments (persist across key tiles)
    short8 qf0 = *(short8*)&Qs[m0 + lcol][quad * 8];
    short8 qf1 = *(short8*)&Qs[m0 + lcol][32 + quad * 8];

    float  m_run[4], l_run[4];
    floatx4 oacc[4];
#pragma unroll
    for (int r = 0; r < 4; ++r) { m_run[r] = -1e30f; l_run[r] = 0.f; }
#pragma unroll
    for (int n = 0; n < 4; ++n) oacc[n] = (floatx4){0.f, 0.f, 0.f, 0.f};

    const int q_glob0 = qt * 64 + m0 + quad * 4;   // + r

    for (int kt = 0; kt < SEQ; kt += 64) {
        __syncthreads();   // previous tile's PV reads done
        {
            // K tile: row-major [key][dk]
            *(short8*)&Ks[strow][stcol]      = *(const short8*)&Kg[(size_t)(kt + strow) * DK + stcol];
            *(short8*)&Ks[strow + 32][stcol] = *(const short8*)&Kg[(size_t)(kt + strow + 32) * DK + stcol];
            // V tile transposed into Vt[d][key]
            ushort8 v0 = *(const ushort8*)&Vg[(size_t)(kt + strow) * DK + stcol];
            ushort8 v1 = *(const ushort8*)&Vg[(size_t)(kt + strow + 32) * DK + stcol];
#pragma unroll
            for (int j = 0; j < 8; ++j) Vt[stcol + j][strow]      = v0[j];
#pragma unroll
            for (int j = 0; j < 8; ++j) Vt[stcol + j][strow + 32] = v1[j];
        }
        __syncthreads();

        // ---- S = Q K^T (4 col tiles x 2 k-halves) ----
        floatx4 s[4];
#pragma unroll
        for (int n = 0; n < 4; ++n) {
            short8 kf0 = *(short8*)&Ks[n * 16 + lcol][quad * 8];
            short8 kf1 = *(short8*)&Ks[n * 16 + lcol][32 + quad * 8];
            floatx4 a = (floatx4){0.f, 0.f, 0.f, 0.f};
            a = __builtin_amdgcn_mfma_f32_16x16x32_bf16(qf0, kf0, a, 0, 0, 0);
            a = __builtin_amdgcn_mfma_f32_16x16x32_bf16(qf1, kf1, a, 0, 0, 0);
            s[n] = a;
        }

        // ---- diagonal mask ----
#pragma unroll
        for (int n = 0; n < 4; ++n) {
            const int kg = kt + n * 16 + lcol;
#pragma unroll
            for (int r = 0; r < 4; ++r)
                if (kg == q_glob0 + r) s[n][r] = -1e30f;
        }

        // ---- online softmax (per query row r) ----
        float alpha[4];
#pragma unroll
        for (int r = 0; r < 4; ++r) {
            float mx = fmaxf(fmaxf(s[0][r], s[1][r]), fmaxf(s[2][r], s[3][r]));
#pragma unroll
            for (int off = 1; off <= 8; off <<= 1)
                mx = fmaxf(mx, __shfl_xor(mx, off, 64));
            const float mnew = fmaxf(m_run[r], mx);
            alpha[r] = __expf(m_run[r] - mnew);
            m_run[r] = mnew;
            float psum = 0.f;
#pragma unroll
            for (int n = 0; n < 4; ++n) {
                const float p = __expf(s[n][r] - mnew);
                s[n][r] = p;
                psum += p;
            }
#pragma unroll
            for (int off = 1; off <= 8; off <<= 1)
                psum += __shfl_xor(psum, off, 64);
            l_run[r] = l_run[r] * alpha[r] + psum;
        }

        // rescale O, spill P to LDS (bf16)
#pragma unroll
        for (int n = 0; n < 4; ++n) {
#pragma unroll
            for (int r = 0; r < 4; ++r) {
                oacc[n][r] *= alpha[r];
                Ps[m0 + quad * 4 + r][n * 16 + lcol] = f2bf(s[n][r]);
            }
        }
        __syncthreads();

        // ---- O += P V ----
        short8 pf0 = *(short8*)&Ps[m0 + lcol][quad * 8];
        short8 pf1 = *(short8*)&Ps[m0 + lcol][32 + quad * 8];
#pragma unroll
        for (int n = 0; n < 4; ++n) {
            short8 vf0 = *(short8*)&Vt[n * 16 + lcol][quad * 8];
            short8 vf1 = *(short8*)&Vt[n * 16 + lcol][32 + quad * 8];
            oacc[n] = __builtin_amdgcn_mfma_f32_16x16x32_bf16(pf0, vf0, oacc[n], 0, 0, 0);
            oacc[n] = __builtin_amdgcn_mfma_f32_16x16x32_bf16(pf1, vf1, oacc[n], 0, 0, 0);
        }
    }

    // ---- epilogue: divide by l, store fp32 to attn_out [B,S,D] ----
    float* obase = attn_out + ((size_t)b * SEQ + (size_t)qt * 64) * D_MODEL + h * DK;
#pragma unroll
    for (int r = 0; r < 4; ++r) {
        const float inv = 1.0f / l_run[r];
        const int qrow = m0 + quad * 4 + r;
#pragma unroll
        for (int n = 0; n < 4; ++n)
            obase[(size_t)qrow * D_MODEL + n * 16 + lcol] = oacc[n][r] * inv;
    }
}

extern "C" void kernel_launch(void* const* d_in, const int* in_sizes, int n_in,
                              void* d_out, int out_size, void* d_ws, size_t ws_size,
                              hipStream_t stream) {
    const float* x     = (const float*)d_in[0];   // [B,S,D]
    const float* w_qkv = (const float*)d_in[1];   // [3D,D]
    const float* w_out = (const float*)d_in[2];   // [D,D]
    const float* b_out = (const float*)d_in[3];   // [D]
    float* out = (float*)d_out;                   // [B,S,D]

    // workspace layout:
    //   Qb, Kb, Vb : bf16 [B,H,S,64]  (8 MB each)
    //   qkv        : fp32 [B,S,3D]    (50 MB)  -- dead after rope_pack
    //   attn_out   : fp32 [B,S,D]     -- aliases qkv (safe: pack completes first)
    const size_t HEADS_ELEMS = (size_t)BATCH * NHEADS * SEQ * DK;   // 4,194,304
    unsigned short* Qb = (unsigned short*)d_ws;
    unsigned short* Kb = Qb + HEADS_ELEMS;
    unsigned short* Vb = Kb + HEADS_ELEMS;
    float* qkv      = (float*)(Vb + HEADS_ELEMS);
    float* attn_out = qkv;   // alias — qkv is dead after rope_pack

    const int M = BATCH * SEQ;        // 4096

    // 1) qkv = x @ w_qkv^T   (fp32)
    {
        dim3 grid(3 * D_MODEL / 64, M / 64);
        gemm_abt<<<grid, 256, 0, stream>>>(x, w_qkv, nullptr, qkv, M, 3 * D_MODEL, D_MODEL);
    }
    // 2) RoPE + bf16 pack (q scaled by 1/8)
    {
        const int total = BATCH * SEQ * NHEADS * (DK / 2);   // 2,097,152... one thread per (b,s,h,pair)
        rope_pack<<<(BATCH * SEQ * NHEADS * 32) / 256, 256, 0, stream>>>(qkv, Qb, Kb, Vb);
    }
    // 3) flash attention
    {
        dim3 grid(SEQ / 64, NHEADS, BATCH);
        flash_attn<<<grid, 256, 0, stream>>>(Qb, Kb, Vb, attn_out);
    }
    // 4) out = attn_out @ w_out^T + b_out  (fp32)
    {
        dim3 grid(D_MODEL / 64, M / 64);
        gemm_abt<<<grid, 256, 0, stream>>>(attn_out, w_out, b_out, out, M, D_MODEL, D_MODEL);
    }
}

// Round 3
// 339.867 us; speedup vs baseline: 16.6800x; 2.7681x over previous
//
#include <hip/hip_runtime.h>
#include <hip/hip_bf16.h>
#include <math.h>

#define D_MODEL 1024
#define NHEADS  16
#define DK      64
#define SEQ     2048
#define BATCH   2

typedef __attribute__((ext_vector_type(8))) short  short8;
typedef __attribute__((ext_vector_type(8))) unsigned short ushort8;
typedef __attribute__((ext_vector_type(4))) float  floatx4;

__device__ __forceinline__ unsigned short f2bf(float f) {
    union { float f; unsigned int u; } v; v.f = f;
    unsigned int u = v.u;
    return (unsigned short)((u + 0x7FFFu + ((u >> 16) & 1u)) >> 16);
}
__device__ __forceinline__ float bf2f(unsigned short u) {
    union { unsigned int u; float f; } v; v.u = ((unsigned int)u) << 16;
    return v.f;
}

// ---------------- fp32 -> bf16 pack (8 elems/thread) ----------------
__global__ __launch_bounds__(256) void pack_bf16(const float* __restrict__ in,
                                                 unsigned short* __restrict__ out,
                                                 int n8) {
    const int t = blockIdx.x * blockDim.x + threadIdx.x;
    if (t >= n8) return;
    const float4 a = ((const float4*)in)[2 * t];
    const float4 b = ((const float4*)in)[2 * t + 1];
    short8 o;
    o[0] = (short)f2bf(a.x); o[1] = (short)f2bf(a.y);
    o[2] = (short)f2bf(a.z); o[3] = (short)f2bf(a.w);
    o[4] = (short)f2bf(b.x); o[5] = (short)f2bf(b.y);
    o[6] = (short)f2bf(b.z); o[7] = (short)f2bf(b.w);
    ((short8*)out)[t] = o;
}

// ---------------- bf16 MFMA GEMM: C[M,N] = A[M,K] @ B[N,K]^T (+bias) ----------------
// 128x128 tile, BK=32, 256 threads = 4 waves, each wave 64x64 (4x4 of 16x16x32).
template <typename OUT_T>
__global__ __launch_bounds__(256) void gemm_bf16(const unsigned short* __restrict__ A,
                                                 const unsigned short* __restrict__ B,
                                                 const float* __restrict__ bias,
                                                 OUT_T* __restrict__ C,
                                                 int M, int N, int K) {
    __shared__ __align__(16) unsigned short As[128][40];   // pad 32->40 (80B rows, 16B aligned)
    __shared__ __align__(16) unsigned short Bs[128][40];

    const int tid  = threadIdx.x;
    const int wave = tid >> 6;
    const int lane = tid & 63;
    const int quad = lane >> 4;
    const int lcol = lane & 15;
    const int wr   = (wave >> 1) * 64;   // wave row base in tile
    const int wc   = (wave & 1) * 64;    // wave col base in tile
    const int tm   = blockIdx.y * 128;
    const int tn   = blockIdx.x * 128;

    const int lr = tid >> 2;             // 0..63 staging row
    const int lc = (tid & 3) * 8;        // 0,8,16,24 staging col

    floatx4 acc[4][4];
#pragma unroll
    for (int i = 0; i < 4; ++i)
#pragma unroll
        for (int j = 0; j < 4; ++j) acc[i][j] = (floatx4){0.f, 0.f, 0.f, 0.f};

    for (int k0 = 0; k0 < K; k0 += 32) {
        const short8 a0 = *(const short8*)&A[(size_t)(tm + lr) * K + k0 + lc];
        const short8 a1 = *(const short8*)&A[(size_t)(tm + 64 + lr) * K + k0 + lc];
        const short8 b0 = *(const short8*)&B[(size_t)(tn + lr) * K + k0 + lc];
        const short8 b1 = *(const short8*)&B[(size_t)(tn + 64 + lr) * K + k0 + lc];
        __syncthreads();   // previous iter's ds_reads done before overwrite
        *(short8*)&As[lr][lc]      = a0;
        *(short8*)&As[lr + 64][lc] = a1;
        *(short8*)&Bs[lr][lc]      = b0;
        *(short8*)&Bs[lr + 64][lc] = b1;
        __syncthreads();

        short8 af[4], bf[4];
#pragma unroll
        for (int i = 0; i < 4; ++i) af[i] = *(short8*)&As[wr + i * 16 + lcol][quad * 8];
#pragma unroll
        for (int j = 0; j < 4; ++j) bf[j] = *(short8*)&Bs[wc + j * 16 + lcol][quad * 8];
#pragma unroll
        for (int i = 0; i < 4; ++i)
#pragma unroll
            for (int j = 0; j < 4; ++j)
                acc[i][j] = __builtin_amdgcn_mfma_f32_16x16x32_bf16(af[i], bf[j], acc[i][j], 0, 0, 0);
    }

    // epilogue: C row = tm + wr + i*16 + quad*4 + r ; col = tn + wc + j*16 + lcol
#pragma unroll
    for (int i = 0; i < 4; ++i) {
#pragma unroll
        for (int r = 0; r < 4; ++r) {
            const int row = tm + wr + i * 16 + quad * 4 + r;
#pragma unroll
            for (int j = 0; j < 4; ++j) {
                const int col = tn + wc + j * 16 + lcol;
                float v = acc[i][j][r];
                if (bias) v += bias[col];
                if constexpr (sizeof(OUT_T) == 2)
                    C[(size_t)row * N + col] = (OUT_T)f2bf(v);
                else
                    C[(size_t)row * N + col] = (OUT_T)v;
            }
        }
    }
}

// ---------------- fused RoPE + layout pack (bf16 qkv -> Qb/Kb/Vb) ----------------
// qkvb bf16 [B,S,3D] -> Qb [B,H,S,64] (scaled 1/8), Kb, Vb [B,H,S,64]
__global__ __launch_bounds__(256) void rope_pack(const unsigned short* __restrict__ qkvb,
                                                 unsigned short* __restrict__ Qb,
                                                 unsigned short* __restrict__ Kb,
                                                 unsigned short* __restrict__ Vb) {
    const int tid = blockIdx.x * blockDim.x + threadIdx.x;
    const int i = tid & 31;                 // pair index 0..31
    const int h = (tid >> 5) & (NHEADS - 1);
    const int s = (tid >> 9) & (SEQ - 1);
    const int b = tid >> 20;
    if (b >= BATCH) return;

    const size_t in_base = ((size_t)(b * SEQ + s)) * (3 * D_MODEL) + h * DK + 2 * i;
    const unsigned short* q2 = &qkvb[in_base];
    const unsigned short* k2 = &qkvb[in_base + D_MODEL];
    const unsigned short* v2 = &qkvb[in_base + 2 * D_MODEL];
    const float q0 = bf2f(q2[0]), q1 = bf2f(q2[1]);
    const float k0 = bf2f(k2[0]), k1 = bf2f(k2[1]);

    const float inv_freq = exp2f(-(2.0f * (float)i / (float)DK) * log2f(50.0f));
    const float angle = (float)s * inv_freq;
    float sn, cs;
    __sincosf(angle, &sn, &cs);

    const size_t out_base = (((size_t)(b * NHEADS + h)) * SEQ + s) * DK + 2 * i;
    Qb[out_base]     = f2bf((q0 * cs - q1 * sn) * 0.125f);
    Qb[out_base + 1] = f2bf((q1 * cs + q0 * sn) * 0.125f);
    Kb[out_base]     = f2bf(k0 * cs - k1 * sn);
    Kb[out_base + 1] = f2bf(k1 * cs + k0 * sn);
    Vb[out_base]     = v2[0];
    Vb[out_base + 1] = v2[1];
}

// ---------------- flash attention, bf16 MFMA ----------------
#define LDW 72

__global__ __launch_bounds__(256, 4) void flash_attn(const unsigned short* __restrict__ Qb,
                                                     const unsigned short* __restrict__ Kb,
                                                     const unsigned short* __restrict__ Vb,
                                                     unsigned short* __restrict__ attn_out) {
    const int qt   = blockIdx.x;
    const int h    = blockIdx.y;
    const int b    = blockIdx.z;
    const int tid  = threadIdx.x;
    const int wave = tid >> 6;
    const int lane = tid & 63;
    const int quad = lane >> 4;
    const int lcol = lane & 15;
    const int m0   = wave * 16;

    __shared__ __align__(16) unsigned short Qs[64][LDW];
    __shared__ __align__(16) unsigned short Ks[64][LDW];
    __shared__ __align__(16) unsigned short Vt[64][LDW];
    __shared__ __align__(16) unsigned short Ps[64][LDW];

    const size_t bh = (size_t)(b * NHEADS + h);
    const unsigned short* Qg = Qb + (bh * SEQ + (size_t)qt * 64) * DK;
    const unsigned short* Kg = Kb + bh * SEQ * DK;
    const unsigned short* Vg = Vb + bh * SEQ * DK;

    const int strow = tid >> 3;           // 0..31
    const int stcol = (tid & 7) * 8;      // 0..56

    *(short8*)&Qs[strow][stcol]      = *(const short8*)&Qg[(size_t)strow * DK + stcol];
    *(short8*)&Qs[strow + 32][stcol] = *(const short8*)&Qg[(size_t)(strow + 32) * DK + stcol];
    __syncthreads();

    short8 qf0 = *(short8*)&Qs[m0 + lcol][quad * 8];
    short8 qf1 = *(short8*)&Qs[m0 + lcol][32 + quad * 8];

    float  m_run[4], l_run[4];
    floatx4 oacc[4];
#pragma unroll
    for (int r = 0; r < 4; ++r) { m_run[r] = -1e30f; l_run[r] = 0.f; }
#pragma unroll
    for (int n = 0; n < 4; ++n) oacc[n] = (floatx4){0.f, 0.f, 0.f, 0.f};

    const int q_glob0 = qt * 64 + m0 + quad * 4;

    for (int kt = 0; kt < SEQ; kt += 64) {
        __syncthreads();
        {
            *(short8*)&Ks[strow][stcol]      = *(const short8*)&Kg[(size_t)(kt + strow) * DK + stcol];
            *(short8*)&Ks[strow + 32][stcol] = *(const short8*)&Kg[(size_t)(kt + strow + 32) * DK + stcol];
            ushort8 v0 = *(const ushort8*)&Vg[(size_t)(kt + strow) * DK + stcol];
            ushort8 v1 = *(const ushort8*)&Vg[(size_t)(kt + strow + 32) * DK + stcol];
#pragma unroll
            for (int j = 0; j < 8; ++j) Vt[stcol + j][strow]      = v0[j];
#pragma unroll
            for (int j = 0; j < 8; ++j) Vt[stcol + j][strow + 32] = v1[j];
        }
        __syncthreads();

        floatx4 s[4];
#pragma unroll
        for (int n = 0; n < 4; ++n) {
            short8 kf0 = *(short8*)&Ks[n * 16 + lcol][quad * 8];
            short8 kf1 = *(short8*)&Ks[n * 16 + lcol][32 + quad * 8];
            floatx4 a = (floatx4){0.f, 0.f, 0.f, 0.f};
            a = __builtin_amdgcn_mfma_f32_16x16x32_bf16(qf0, kf0, a, 0, 0, 0);
            a = __builtin_amdgcn_mfma_f32_16x16x32_bf16(qf1, kf1, a, 0, 0, 0);
            s[n] = a;
        }

#pragma unroll
        for (int n = 0; n < 4; ++n) {
            const int kg = kt + n * 16 + lcol;
#pragma unroll
            for (int r = 0; r < 4; ++r)
                if (kg == q_glob0 + r) s[n][r] = -1e30f;
        }

        float alpha[4];
#pragma unroll
        for (int r = 0; r < 4; ++r) {
            float mx = fmaxf(fmaxf(s[0][r], s[1][r]), fmaxf(s[2][r], s[3][r]));
#pragma unroll
            for (int off = 1; off <= 8; off <<= 1)
                mx = fmaxf(mx, __shfl_xor(mx, off, 64));
            const float mnew = fmaxf(m_run[r], mx);
            alpha[r] = __expf(m_run[r] - mnew);
            m_run[r] = mnew;
            float psum = 0.f;
#pragma unroll
            for (int n = 0; n < 4; ++n) {
                const float p = __expf(s[n][r] - mnew);
                s[n][r] = p;
                psum += p;
            }
#pragma unroll
            for (int off = 1; off <= 8; off <<= 1)
                psum += __shfl_xor(psum, off, 64);
            l_run[r] = l_run[r] * alpha[r] + psum;
        }

#pragma unroll
        for (int n = 0; n < 4; ++n) {
#pragma unroll
            for (int r = 0; r < 4; ++r) {
                oacc[n][r] *= alpha[r];
                Ps[m0 + quad * 4 + r][n * 16 + lcol] = f2bf(s[n][r]);
            }
        }
        __syncthreads();

        short8 pf0 = *(short8*)&Ps[m0 + lcol][quad * 8];
        short8 pf1 = *(short8*)&Ps[m0 + lcol][32 + quad * 8];
#pragma unroll
        for (int n = 0; n < 4; ++n) {
            short8 vf0 = *(short8*)&Vt[n * 16 + lcol][quad * 8];
            short8 vf1 = *(short8*)&Vt[n * 16 + lcol][32 + quad * 8];
            oacc[n] = __builtin_amdgcn_mfma_f32_16x16x32_bf16(pf0, vf0, oacc[n], 0, 0, 0);
            oacc[n] = __builtin_amdgcn_mfma_f32_16x16x32_bf16(pf1, vf1, oacc[n], 0, 0, 0);
        }
    }

    // epilogue: bf16 store to attn_out [B,S,D]
    unsigned short* obase = attn_out + ((size_t)b * SEQ + (size_t)qt * 64) * D_MODEL + h * DK;
#pragma unroll
    for (int r = 0; r < 4; ++r) {
        const float inv = 1.0f / l_run[r];
        const int qrow = m0 + quad * 4 + r;
#pragma unroll
        for (int n = 0; n < 4; ++n)
            obase[(size_t)qrow * D_MODEL + n * 16 + lcol] = f2bf(oacc[n][r] * inv);
    }
}

extern "C" void kernel_launch(void* const* d_in, const int* in_sizes, int n_in,
                              void* d_out, int out_size, void* d_ws, size_t ws_size,
                              hipStream_t stream) {
    const float* x     = (const float*)d_in[0];   // [B,S,D]
    const float* w_qkv = (const float*)d_in[1];   // [3D,D]
    const float* w_out = (const float*)d_in[2];   // [D,D]
    const float* b_out = (const float*)d_in[3];   // [D]
    float* out = (float*)d_out;                   // [B,S,D]

    const int M = BATCH * SEQ;                    // 4096
    const size_t X_ELEMS   = (size_t)M * D_MODEL;            // 4.19M
    const size_t WQKV_ELEMS= (size_t)3 * D_MODEL * D_MODEL;  // 3.15M
    const size_t WOUT_ELEMS= (size_t)D_MODEL * D_MODEL;      // 1.05M
    const size_t QKV_ELEMS = (size_t)M * 3 * D_MODEL;        // 12.6M
    const size_t HEAD_ELEMS= (size_t)BATCH * NHEADS * SEQ * DK; // 4.19M

    unsigned short* xb     = (unsigned short*)d_ws;
    unsigned short* wqkvb  = xb + X_ELEMS;
    unsigned short* woutb  = wqkvb + WQKV_ELEMS;
    unsigned short* qkvb   = woutb + WOUT_ELEMS;
    unsigned short* Qb     = qkvb + QKV_ELEMS;
    unsigned short* Kb     = Qb + HEAD_ELEMS;
    unsigned short* Vb     = Kb + HEAD_ELEMS;
    unsigned short* attnb  = Vb + HEAD_ELEMS;     // [B,S,D] bf16

    // 0) pack inputs to bf16
    pack_bf16<<<(int)(X_ELEMS / 8 + 255) / 256, 256, 0, stream>>>(x, xb, (int)(X_ELEMS / 8));
    pack_bf16<<<(int)(WQKV_ELEMS / 8 + 255) / 256, 256, 0, stream>>>(w_qkv, wqkvb, (int)(WQKV_ELEMS / 8));
    pack_bf16<<<(int)(WOUT_ELEMS / 8 + 255) / 256, 256, 0, stream>>>(w_out, woutb, (int)(WOUT_ELEMS / 8));

    // 1) qkvb = xb @ wqkvb^T   (bf16 out)
    {
        dim3 grid(3 * D_MODEL / 128, M / 128);
        gemm_bf16<unsigned short><<<grid, 256, 0, stream>>>(xb, wqkvb, nullptr, qkvb,
                                                            M, 3 * D_MODEL, D_MODEL);
    }
    // 2) RoPE + head-major pack
    rope_pack<<<(BATCH * SEQ * NHEADS * 32) / 256, 256, 0, stream>>>(qkvb, Qb, Kb, Vb);

    // 3) flash attention (bf16 out)
    {
        dim3 grid(SEQ / 64, NHEADS, BATCH);
        flash_attn<<<grid, 256, 0, stream>>>(Qb, Kb, Vb, attnb);
    }
    // 4) out = attnb @ woutb^T + b_out  (fp32 out)
    {
        dim3 grid(D_MODEL / 128, M / 128);
        gemm_bf16<float><<<grid, 256, 0, stream>>>(attnb, woutb, b_out, out,
                                                   M, D_MODEL, D_MODEL);
    }
}

// Round 4
// 244.094 us; speedup vs baseline: 23.2246x; 1.3924x over previous
//
#include <hip/hip_runtime.h>
#include <hip/hip_bf16.h>
#include <math.h>

#define D_MODEL 1024
#define NHEADS  16
#define DK      64
#define SEQ     2048
#define BATCH   2

typedef __attribute__((ext_vector_type(8))) short  short8;
typedef __attribute__((ext_vector_type(8))) unsigned short ushort8;
typedef __attribute__((ext_vector_type(4))) float  floatx4;

__device__ __forceinline__ unsigned short f2bf(float f) {
    union { float f; unsigned int u; } v; v.f = f;
    unsigned int u = v.u;
    return (unsigned short)((u + 0x7FFFu + ((u >> 16) & 1u)) >> 16);
}
__device__ __forceinline__ float bf2f(unsigned short u) {
    union { unsigned int u; float f; } v; v.u = ((unsigned int)u) << 16;
    return v.f;
}

// async global->LDS, 16B per lane. LDS dest = wave-uniform base + lane*16.
__device__ __forceinline__ void gload_lds16(const unsigned short* g, unsigned short* l) {
    __builtin_amdgcn_global_load_lds((__attribute__((address_space(1))) const void*)g,
                                     (__attribute__((address_space(3))) void*)l,
                                     16, 0, 0);
}

// ---------------- fp32 -> bf16 pack (8 elems/thread) ----------------
__global__ __launch_bounds__(256) void pack_bf16(const float* __restrict__ in,
                                                 unsigned short* __restrict__ out,
                                                 int n8) {
    const int t = blockIdx.x * blockDim.x + threadIdx.x;
    if (t >= n8) return;
    const float4 a = ((const float4*)in)[2 * t];
    const float4 b = ((const float4*)in)[2 * t + 1];
    short8 o;
    o[0] = (short)f2bf(a.x); o[1] = (short)f2bf(a.y);
    o[2] = (short)f2bf(a.z); o[3] = (short)f2bf(a.w);
    o[4] = (short)f2bf(b.x); o[5] = (short)f2bf(b.y);
    o[6] = (short)f2bf(b.z); o[7] = (short)f2bf(b.w);
    ((short8*)out)[t] = o;
}

// ---------------- bf16 MFMA GEMM (m97 structure): C = A @ B^T (+bias) ----------------
// 128x128 tile, BK=32, 256 threads = 4 waves, global_load_lds staging, unpadded LDS.
template <typename OUT_T>
__global__ __launch_bounds__(256) void gemm_bf16(const unsigned short* __restrict__ A,
                                                 const unsigned short* __restrict__ B,
                                                 const float* __restrict__ bias,
                                                 OUT_T* __restrict__ C,
                                                 int M, int N, int K) {
    __shared__ __align__(16) unsigned short As[128][32];
    __shared__ __align__(16) unsigned short Bs[128][32];

    const int tid  = threadIdx.x;
    const int wave = tid >> 6;
    const int lane = tid & 63;
    const int quad = lane >> 4;
    const int lcol = lane & 15;
    const int wr   = (wave >> 1) * 64;
    const int wc   = (wave & 1) * 64;
    const int tm   = blockIdx.y * 128;
    const int tn   = blockIdx.x * 128;

    // staging: wave w covers rows [w*32, w*32+32) in two 16-row issues.
    const int srow = wave * 32 + (lane >> 2);   // +16 for second issue
    const int scol = (lane & 3) * 8;
    const unsigned short* gA0 = A + (size_t)(tm + srow) * K + scol;
    const unsigned short* gA1 = gA0 + (size_t)16 * K;
    const unsigned short* gB0 = B + (size_t)(tn + srow) * K + scol;
    const unsigned short* gB1 = gB0 + (size_t)16 * K;
    unsigned short* lA0 = &As[wave * 32][0];
    unsigned short* lA1 = &As[wave * 32 + 16][0];
    unsigned short* lB0 = &Bs[wave * 32][0];
    unsigned short* lB1 = &Bs[wave * 32 + 16][0];

    floatx4 acc[4][4];
#pragma unroll
    for (int i = 0; i < 4; ++i)
#pragma unroll
        for (int j = 0; j < 4; ++j) acc[i][j] = (floatx4){0.f, 0.f, 0.f, 0.f};

    for (int k0 = 0; k0 < K; k0 += 32) {
        __syncthreads();                       // prior frag reads complete
        gload_lds16(gA0 + k0, lA0);
        gload_lds16(gA1 + k0, lA1);
        gload_lds16(gB0 + k0, lB0);
        gload_lds16(gB1 + k0, lB1);
        __syncthreads();                       // drains vmcnt(0) -> tile resident

        short8 af[4], bf[4];
#pragma unroll
        for (int i = 0; i < 4; ++i) af[i] = *(short8*)&As[wr + i * 16 + lcol][quad * 8];
#pragma unroll
        for (int j = 0; j < 4; ++j) bf[j] = *(short8*)&Bs[wc + j * 16 + lcol][quad * 8];
#pragma unroll
        for (int i = 0; i < 4; ++i)
#pragma unroll
            for (int j = 0; j < 4; ++j)
                acc[i][j] = __builtin_amdgcn_mfma_f32_16x16x32_bf16(af[i], bf[j], acc[i][j], 0, 0, 0);
    }

#pragma unroll
    for (int i = 0; i < 4; ++i) {
#pragma unroll
        for (int r = 0; r < 4; ++r) {
            const int row = tm + wr + i * 16 + quad * 4 + r;
#pragma unroll
            for (int j = 0; j < 4; ++j) {
                const int col = tn + wc + j * 16 + lcol;
                float v = acc[i][j][r];
                if (bias) v += bias[col];
                if constexpr (sizeof(OUT_T) == 2)
                    C[(size_t)row * N + col] = (OUT_T)f2bf(v);
                else
                    C[(size_t)row * N + col] = (OUT_T)v;
            }
        }
    }
}

// ---------------- RoPE + head-major pack (Q scaled 1/8; K) ----------------
__global__ __launch_bounds__(256) void rope_pack(const unsigned short* __restrict__ qkvb,
                                                 unsigned short* __restrict__ Qb,
                                                 unsigned short* __restrict__ Kb) {
    const int tid = blockIdx.x * blockDim.x + threadIdx.x;
    const int i = tid & 31;
    const int h = (tid >> 5) & (NHEADS - 1);
    const int s = (tid >> 9) & (SEQ - 1);
    const int b = tid >> 20;
    if (b >= BATCH) return;

    const size_t in_base = ((size_t)(b * SEQ + s)) * (3 * D_MODEL) + h * DK + 2 * i;
    const float q0 = bf2f(qkvb[in_base]),           q1 = bf2f(qkvb[in_base + 1]);
    const float k0 = bf2f(qkvb[in_base + D_MODEL]), k1 = bf2f(qkvb[in_base + D_MODEL + 1]);

    const float inv_freq = exp2f(-(2.0f * (float)i / (float)DK) * log2f(50.0f));
    float sn, cs;
    __sincosf((float)s * inv_freq, &sn, &cs);

    const size_t out_base = (((size_t)(b * NHEADS + h)) * SEQ + s) * DK + 2 * i;
    Qb[out_base]     = f2bf((q0 * cs - q1 * sn) * 0.125f);
    Qb[out_base + 1] = f2bf((q1 * cs + q0 * sn) * 0.125f);
    Kb[out_base]     = f2bf(k0 * cs - k1 * sn);
    Kb[out_base + 1] = f2bf(k1 * cs + k0 * sn);
}

// ---------------- V transpose: qkvb V-slice [B,S,3D] -> Vt_g [B,H,64,S] ----------------
__global__ __launch_bounds__(256) void vtrans(const unsigned short* __restrict__ qkvb,
                                              unsigned short* __restrict__ Vtg) {
    const int st = blockIdx.x, h = blockIdx.y, b = blockIdx.z;
    __shared__ unsigned short Lt[64][65];
    const int tid = threadIdx.x;
    const int r = tid >> 3;                 // 0..31
    const int c = (tid & 7) * 8;
    const int s0 = st * 64;

    const size_t in_row = ((size_t)(b * SEQ + s0 + r)) * (3 * D_MODEL) + 2 * D_MODEL + h * DK + c;
    const ushort8 v0 = *(const ushort8*)&qkvb[in_row];
    const ushort8 v1 = *(const ushort8*)&qkvb[in_row + (size_t)32 * (3 * D_MODEL)];
#pragma unroll
    for (int j = 0; j < 8; ++j) Lt[c + j][r]      = v0[j];
#pragma unroll
    for (int j = 0; j < 8; ++j) Lt[c + j][r + 32] = v1[j];
    __syncthreads();

    const size_t bh = (size_t)(b * NHEADS + h);
    ushort8 o0, o1;
#pragma unroll
    for (int j = 0; j < 8; ++j) { o0[j] = Lt[r][c + j]; o1[j] = Lt[r + 32][c + j]; }
    unsigned short* orow = Vtg + (bh * DK + r) * SEQ + s0 + c;
    *(ushort8*)orow = o0;
    *(ushort8*)(orow + (size_t)32 * SEQ) = o1;
}

// ---------------- flash attention, deferred softmax ----------------
// Scores ~N(0,1): max < ~8, exp(s) < 3e3, row sums < ~4e3 -> safe in fp32 without
// max subtraction. No per-tile reductions; one cross-lane l-reduction at the end.
#define LDW 72

__global__ __launch_bounds__(256) void flash_attn(const unsigned short* __restrict__ Qb,
                                                  const unsigned short* __restrict__ Kb,
                                                  const unsigned short* __restrict__ Vtg,
                                                  unsigned short* __restrict__ attnb) {
    const int qt   = blockIdx.x;
    const int h    = blockIdx.y;
    const int b    = blockIdx.z;
    const int tid  = threadIdx.x;
    const int wave = tid >> 6;
    const int lane = tid & 63;
    const int quad = lane >> 4;
    const int lcol = lane & 15;
    const int m0   = wave * 16;

    __shared__ __align__(16) unsigned short Ks[64][LDW];
    __shared__ __align__(16) unsigned short Vt[64][LDW];   // Vt[d][key]
    __shared__ __align__(16) unsigned short Ps[64][LDW];

    const size_t bh = (size_t)(b * NHEADS + h);
    const unsigned short* Qg = Qb + (bh * SEQ + (size_t)qt * 64) * DK;
    const unsigned short* Kg = Kb + bh * SEQ * DK;
    const unsigned short* Vg = Vtg + bh * (size_t)DK * SEQ;

    // Q fragments straight from global (one-time)
    const unsigned short* qrow = Qg + (size_t)(m0 + lcol) * DK;
    const short8 qf0 = *(const short8*)&qrow[quad * 8];
    const short8 qf1 = *(const short8*)&qrow[32 + quad * 8];

    const int strow = tid >> 3;           // 0..31
    const int stcol = (tid & 7) * 8;
    const unsigned short* kg0 = &Kg[(size_t)strow * DK + stcol];
    const unsigned short* kg1 = &Kg[(size_t)(strow + 32) * DK + stcol];
    const unsigned short* vg0 = &Vg[(size_t)strow * SEQ + stcol];
    const unsigned short* vg1 = &Vg[(size_t)(strow + 32) * SEQ + stcol];

    // prefetch tile 0
    short8 kr0 = *(const short8*)&kg0[0];
    short8 kr1 = *(const short8*)&kg1[0];
    short8 vr0 = *(const short8*)&vg0[0];
    short8 vr1 = *(const short8*)&vg1[0];

    floatx4 oacc[4];
    float lp[4];
#pragma unroll
    for (int n = 0; n < 4; ++n) oacc[n] = (floatx4){0.f, 0.f, 0.f, 0.f};
#pragma unroll
    for (int r = 0; r < 4; ++r) lp[r] = 0.f;

    const int q_glob0 = qt * 64 + m0 + quad * 4;

    for (int kt = 0; kt < SEQ; kt += 64) {
        __syncthreads();                  // all waves done reading prev Ks/Vt
        *(short8*)&Ks[strow][stcol]      = kr0;
        *(short8*)&Ks[strow + 32][stcol] = kr1;
        *(short8*)&Vt[strow][stcol]      = vr0;
        *(short8*)&Vt[strow + 32][stcol] = vr1;
        __syncthreads();

        // prefetch next tile (overlaps with compute below)
        const int ktn = (kt + 64 < SEQ) ? kt + 64 : 0;
        kr0 = *(const short8*)&kg0[(size_t)ktn * DK];
        kr1 = *(const short8*)&kg1[(size_t)ktn * DK];
        vr0 = *(const short8*)&vg0[ktn];
        vr1 = *(const short8*)&vg1[ktn];

        // ---- S = Q K^T ----
        floatx4 s[4];
#pragma unroll
        for (int n = 0; n < 4; ++n) {
            short8 kf0 = *(short8*)&Ks[n * 16 + lcol][quad * 8];
            short8 kf1 = *(short8*)&Ks[n * 16 + lcol][32 + quad * 8];
            floatx4 a = (floatx4){0.f, 0.f, 0.f, 0.f};
            a = __builtin_amdgcn_mfma_f32_16x16x32_bf16(qf0, kf0, a, 0, 0, 0);
            a = __builtin_amdgcn_mfma_f32_16x16x32_bf16(qf1, kf1, a, 0, 0, 0);
            s[n] = a;
        }

        // ---- P = exp(S), diagonal -> 0, accumulate row sums ----
#pragma unroll
        for (int n = 0; n < 4; ++n) {
            const int kg = kt + n * 16 + lcol;
#pragma unroll
            for (int r = 0; r < 4; ++r) {
                const float p = (kg == q_glob0 + r) ? 0.f : __expf(s[n][r]);
                lp[r] += p;
                Ps[m0 + quad * 4 + r][n * 16 + lcol] = f2bf(p);
            }
        }
        // Ps is wave-local (each wave writes & reads only rows [m0, m0+16)) -> no barrier

        // ---- O += P V ----
        short8 pf0 = *(short8*)&Ps[m0 + lcol][quad * 8];
        short8 pf1 = *(short8*)&Ps[m0 + lcol][32 + quad * 8];
#pragma unroll
        for (int n = 0; n < 4; ++n) {
            short8 vf0 = *(short8*)&Vt[n * 16 + lcol][quad * 8];
            short8 vf1 = *(short8*)&Vt[n * 16 + lcol][32 + quad * 8];
            oacc[n] = __builtin_amdgcn_mfma_f32_16x16x32_bf16(pf0, vf0, oacc[n], 0, 0, 0);
            oacc[n] = __builtin_amdgcn_mfma_f32_16x16x32_bf16(pf1, vf1, oacc[n], 0, 0, 0);
        }
    }

    // ---- final l reduction (within each quad's 16 lanes) ----
#pragma unroll
    for (int r = 0; r < 4; ++r) {
#pragma unroll
        for (int off = 1; off <= 8; off <<= 1)
            lp[r] += __shfl_xor(lp[r], off, 64);
    }

    unsigned short* obase = attnb + ((size_t)b * SEQ + (size_t)qt * 64) * D_MODEL + h * DK;
#pragma unroll
    for (int r = 0; r < 4; ++r) {
        const float inv = 1.0f / lp[r];
        const int qrow2 = m0 + quad * 4 + r;
#pragma unroll
        for (int n = 0; n < 4; ++n)
            obase[(size_t)qrow2 * D_MODEL + n * 16 + lcol] = f2bf(oacc[n][r] * inv);
    }
}

extern "C" void kernel_launch(void* const* d_in, const int* in_sizes, int n_in,
                              void* d_out, int out_size, void* d_ws, size_t ws_size,
                              hipStream_t stream) {
    const float* x     = (const float*)d_in[0];
    const float* w_qkv = (const float*)d_in[1];
    const float* w_out = (const float*)d_in[2];
    const float* b_out = (const float*)d_in[3];
    float* out = (float*)d_out;

    const int M = BATCH * SEQ;                                   // 4096
    const size_t X_ELEMS    = (size_t)M * D_MODEL;
    const size_t WQKV_ELEMS = (size_t)3 * D_MODEL * D_MODEL;
    const size_t WOUT_ELEMS = (size_t)D_MODEL * D_MODEL;
    const size_t QKV_ELEMS  = (size_t)M * 3 * D_MODEL;
    const size_t HEAD_ELEMS = (size_t)BATCH * NHEADS * SEQ * DK;

    unsigned short* xb    = (unsigned short*)d_ws;
    unsigned short* wqkvb = xb + X_ELEMS;
    unsigned short* woutb = wqkvb + WQKV_ELEMS;
    unsigned short* qkvb  = woutb + WOUT_ELEMS;
    unsigned short* Qb    = qkvb + QKV_ELEMS;
    unsigned short* Kb    = Qb + HEAD_ELEMS;
    unsigned short* Vtg   = Kb + HEAD_ELEMS;                     // [B,H,64,S]
    unsigned short* attnb = Vtg + HEAD_ELEMS;

    // 0) pack to bf16
    pack_bf16<<<(int)(X_ELEMS / 8 + 255) / 256, 256, 0, stream>>>(x, xb, (int)(X_ELEMS / 8));
    pack_bf16<<<(int)(WQKV_ELEMS / 8 + 255) / 256, 256, 0, stream>>>(w_qkv, wqkvb, (int)(WQKV_ELEMS / 8));
    pack_bf16<<<(int)(WOUT_ELEMS / 8 + 255) / 256, 256, 0, stream>>>(w_out, woutb, (int)(WOUT_ELEMS / 8));

    // 1) qkvb = xb @ wqkvb^T
    {
        dim3 grid(3 * D_MODEL / 128, M / 128);
        gemm_bf16<unsigned short><<<grid, 256, 0, stream>>>(xb, wqkvb, nullptr, qkvb,
                                                            M, 3 * D_MODEL, D_MODEL);
    }
    // 2) RoPE pack (Q,K) + V transpose
    rope_pack<<<(BATCH * SEQ * NHEADS * 32) / 256, 256, 0, stream>>>(qkvb, Qb, Kb);
    {
        dim3 grid(SEQ / 64, NHEADS, BATCH);
        vtrans<<<grid, 256, 0, stream>>>(qkvb, Vtg);
    }
    // 3) flash attention
    {
        dim3 grid(SEQ / 64, NHEADS, BATCH);
        flash_attn<<<grid, 256, 0, stream>>>(Qb, Kb, Vtg, attnb);
    }
    // 4) out = attnb @ woutb^T + b_out
    {
        dim3 grid(D_MODEL / 128, M / 128);
        gemm_bf16<float><<<grid, 256, 0, stream>>>(attnb, woutb, b_out, out,
                                                   M, D_MODEL, D_MODEL);
    }
}

// Round 5
// 233.906 us; speedup vs baseline: 24.2362x; 1.0436x over previous
//
#include <hip/hip_runtime.h>
#include <hip/hip_bf16.h>
#include <math.h>

#define D_MODEL 1024
#define NHEADS  16
#define DK      64
#define SEQ     2048
#define BATCH   2
#define QTILE   128

typedef __attribute__((ext_vector_type(8))) short  short8;
typedef __attribute__((ext_vector_type(8))) unsigned short ushort8;
typedef __attribute__((ext_vector_type(4))) float  floatx4;

__device__ __forceinline__ unsigned short f2bf(float f) {      // RNE
    union { float f; unsigned int u; } v; v.f = f;
    unsigned int u = v.u;
    return (unsigned short)((u + 0x7FFFu + ((u >> 16) & 1u)) >> 16);
}
__device__ __forceinline__ unsigned short f2bf_fast(float f) { // round-half-up, 2 ops
    union { float f; unsigned int u; } v; v.f = f;
    return (unsigned short)((v.u + 0x8000u) >> 16);
}
__device__ __forceinline__ float bf2f(unsigned short u) {
    union { unsigned int u; float f; } v; v.u = ((unsigned int)u) << 16;
    return v.f;
}

// async global->LDS, 16B per lane. LDS dest = wave-uniform base + lane*16.
__device__ __forceinline__ void gload_lds16(const unsigned short* g, unsigned short* l) {
    __builtin_amdgcn_global_load_lds((__attribute__((address_space(1))) const void*)g,
                                     (__attribute__((address_space(3))) void*)l,
                                     16, 0, 0);
}

// ---------------- fused fp32 -> bf16 pack of x, w_qkv, w_out ----------------
#define X8 ((BATCH * SEQ * D_MODEL) / 8)
#define W8 ((3 * D_MODEL * D_MODEL) / 8)
#define O8 ((D_MODEL * D_MODEL) / 8)
__global__ __launch_bounds__(256) void pack_all(const float* __restrict__ x,
                                                const float* __restrict__ wq,
                                                const float* __restrict__ wo,
                                                unsigned short* __restrict__ xb,
                                                unsigned short* __restrict__ wqb,
                                                unsigned short* __restrict__ wob) {
    const int t = blockIdx.x * blockDim.x + threadIdx.x;
    const float* src; unsigned short* dst; int idx;
    if (t < X8)           { src = x;  dst = xb;  idx = t; }
    else if (t < X8 + W8) { src = wq; dst = wqb; idx = t - X8; }
    else if (t < X8 + W8 + O8) { src = wo; dst = wob; idx = t - X8 - W8; }
    else return;
    const float4 a = ((const float4*)src)[2 * idx];
    const float4 b = ((const float4*)src)[2 * idx + 1];
    short8 o;
    o[0] = (short)f2bf(a.x); o[1] = (short)f2bf(a.y);
    o[2] = (short)f2bf(a.z); o[3] = (short)f2bf(a.w);
    o[4] = (short)f2bf(b.x); o[5] = (short)f2bf(b.y);
    o[6] = (short)f2bf(b.z); o[7] = (short)f2bf(b.w);
    ((short8*)dst)[idx] = o;
}

// ---------------- bf16 MFMA GEMM (m97 structure): C = A @ B^T (+bias) ----------------
template <typename OUT_T>
__global__ __launch_bounds__(256) void gemm_bf16(const unsigned short* __restrict__ A,
                                                 const unsigned short* __restrict__ B,
                                                 const float* __restrict__ bias,
                                                 OUT_T* __restrict__ C,
                                                 int M, int N, int K) {
    __shared__ __align__(16) unsigned short As[128][32];
    __shared__ __align__(16) unsigned short Bs[128][32];

    const int tid  = threadIdx.x;
    const int wave = tid >> 6;
    const int lane = tid & 63;
    const int quad = lane >> 4;
    const int lcol = lane & 15;
    const int wr   = (wave >> 1) * 64;
    const int wc   = (wave & 1) * 64;
    const int tm   = blockIdx.y * 128;
    const int tn   = blockIdx.x * 128;

    const int srow = wave * 32 + (lane >> 2);
    const int scol = (lane & 3) * 8;
    const unsigned short* gA0 = A + (size_t)(tm + srow) * K + scol;
    const unsigned short* gA1 = gA0 + (size_t)16 * K;
    const unsigned short* gB0 = B + (size_t)(tn + srow) * K + scol;
    const unsigned short* gB1 = gB0 + (size_t)16 * K;
    unsigned short* lA0 = &As[wave * 32][0];
    unsigned short* lA1 = &As[wave * 32 + 16][0];
    unsigned short* lB0 = &Bs[wave * 32][0];
    unsigned short* lB1 = &Bs[wave * 32 + 16][0];

    floatx4 acc[4][4];
#pragma unroll
    for (int i = 0; i < 4; ++i)
#pragma unroll
        for (int j = 0; j < 4; ++j) acc[i][j] = (floatx4){0.f, 0.f, 0.f, 0.f};

    for (int k0 = 0; k0 < K; k0 += 32) {
        __syncthreads();
        gload_lds16(gA0 + k0, lA0);
        gload_lds16(gA1 + k0, lA1);
        gload_lds16(gB0 + k0, lB0);
        gload_lds16(gB1 + k0, lB1);
        __syncthreads();

        short8 af[4], bf[4];
#pragma unroll
        for (int i = 0; i < 4; ++i) af[i] = *(short8*)&As[wr + i * 16 + lcol][quad * 8];
#pragma unroll
        for (int j = 0; j < 4; ++j) bf[j] = *(short8*)&Bs[wc + j * 16 + lcol][quad * 8];
#pragma unroll
        for (int i = 0; i < 4; ++i)
#pragma unroll
            for (int j = 0; j < 4; ++j)
                acc[i][j] = __builtin_amdgcn_mfma_f32_16x16x32_bf16(af[i], bf[j], acc[i][j], 0, 0, 0);
    }

#pragma unroll
    for (int i = 0; i < 4; ++i) {
#pragma unroll
        for (int r = 0; r < 4; ++r) {
            const int row = tm + wr + i * 16 + quad * 4 + r;
#pragma unroll
            for (int j = 0; j < 4; ++j) {
                const int col = tn + wc + j * 16 + lcol;
                float v = acc[i][j][r];
                if (bias) v += bias[col];
                if constexpr (sizeof(OUT_T) == 2)
                    C[(size_t)row * N + col] = (OUT_T)f2bf(v);
                else
                    C[(size_t)row * N + col] = (OUT_T)v;
            }
        }
    }
}

// ---------------- fused RoPE pack (Q*0.125*log2e, K) + V transpose ----------------
// One block per (s-tile of 64, h, b). Qb/Kb [B,H,S,64]; Vtg [B,H,64,S].
__global__ __launch_bounds__(256) void rope_vtrans(const unsigned short* __restrict__ qkvb,
                                                   unsigned short* __restrict__ Qb,
                                                   unsigned short* __restrict__ Kb,
                                                   unsigned short* __restrict__ Vtg) {
    const int st = blockIdx.x, h = blockIdx.y, b = blockIdx.z;
    const int tid = threadIdx.x;
    const int s0 = st * 64;

    // ---- RoPE on Q,K: 8 passes x (8 rows x 32 pairs) ----
    const int i  = tid & 31;
    const int r0 = tid >> 5;                   // 0..7
    const float inv_freq = exp2f(-(2.0f * (float)i / (float)DK) * log2f(50.0f));
    const float QSCALE = 0.125f * 1.44269504f; // fold 1/sqrt(dk) * log2(e)
#pragma unroll
    for (int pass = 0; pass < 8; ++pass) {
        const int s = s0 + r0 + pass * 8;
        const size_t in_base = ((size_t)(b * SEQ + s)) * (3 * D_MODEL) + h * DK + 2 * i;
        const float q0 = bf2f(qkvb[in_base]),           q1 = bf2f(qkvb[in_base + 1]);
        const float k0 = bf2f(qkvb[in_base + D_MODEL]), k1 = bf2f(qkvb[in_base + D_MODEL + 1]);
        float sn, cs;
        __sincosf((float)s * inv_freq, &sn, &cs);
        const size_t ob = (((size_t)(b * NHEADS + h)) * SEQ + s) * DK + 2 * i;
        const unsigned int qw = (unsigned int)f2bf((q0 * cs - q1 * sn) * QSCALE)
                              | ((unsigned int)f2bf((q1 * cs + q0 * sn) * QSCALE) << 16);
        const unsigned int kw = (unsigned int)f2bf(k0 * cs - k1 * sn)
                              | ((unsigned int)f2bf(k1 * cs + k0 * sn) << 16);
        *(unsigned int*)&Qb[ob] = qw;
        *(unsigned int*)&Kb[ob] = kw;
    }

    // ---- V transpose ----
    __shared__ unsigned short Lt[64][65];
    const int r = tid >> 3;                    // 0..31
    const int c = (tid & 7) * 8;
    const size_t in_row = ((size_t)(b * SEQ + s0 + r)) * (3 * D_MODEL) + 2 * D_MODEL + h * DK + c;
    const ushort8 v0 = *(const ushort8*)&qkvb[in_row];
    const ushort8 v1 = *(const ushort8*)&qkvb[in_row + (size_t)32 * (3 * D_MODEL)];
#pragma unroll
    for (int j = 0; j < 8; ++j) Lt[c + j][r]      = v0[j];
#pragma unroll
    for (int j = 0; j < 8; ++j) Lt[c + j][r + 32] = v1[j];
    __syncthreads();
    const size_t bh = (size_t)(b * NHEADS + h);
    ushort8 o0, o1;
#pragma unroll
    for (int j = 0; j < 8; ++j) { o0[j] = Lt[r][c + j]; o1[j] = Lt[r + 32][c + j]; }
    unsigned short* orow = Vtg + (bh * DK + r) * SEQ + s0 + c;
    *(ushort8*)orow = o0;
    *(ushort8*)(orow + (size_t)32 * SEQ) = o1;
}

// ---------------- flash attention: 128-q tile, deferred softmax, exp2 ----------------
#define LDW 72

__global__ __launch_bounds__(256) void flash_attn(const unsigned short* __restrict__ Qb,
                                                  const unsigned short* __restrict__ Kb,
                                                  const unsigned short* __restrict__ Vtg,
                                                  unsigned short* __restrict__ attnb) {
    const int qt   = blockIdx.x;              // 0..15 (tiles of 128 queries)
    const int h    = blockIdx.y;
    const int b    = blockIdx.z;
    const int tid  = threadIdx.x;
    const int wave = tid >> 6;
    const int lane = tid & 63;
    const int quad = lane >> 4;
    const int lcol = lane & 15;
    const int wq0  = wave * 32;               // wave's q-row base in the 128-tile

    __shared__ __align__(16) unsigned short Ks[64][LDW];
    __shared__ __align__(16) unsigned short Vt[64][LDW];    // [d][key]
    __shared__ __align__(16) unsigned short Ps[QTILE][LDW];

    const size_t bh = (size_t)(b * NHEADS + h);
    const unsigned short* Qg = Qb + (bh * SEQ + (size_t)qt * QTILE) * DK;
    const unsigned short* Kg = Kb + bh * SEQ * DK;
    const unsigned short* Vg = Vtg + bh * (size_t)DK * SEQ;

    // Q fragments (2 m-tiles x 2 k-halves), persist in registers
    short8 qf[2][2];
#pragma unroll
    for (int mi = 0; mi < 2; ++mi)
#pragma unroll
        for (int hf = 0; hf < 2; ++hf)
            qf[mi][hf] = *(const short8*)&Qg[(size_t)(wq0 + mi * 16 + lcol) * DK + hf * 32 + quad * 8];

    const int strow = tid >> 3;               // 0..31
    const int stcol = (tid & 7) * 8;
    const unsigned short* kg0 = &Kg[(size_t)strow * DK + stcol];
    const unsigned short* kg1 = &Kg[(size_t)(strow + 32) * DK + stcol];
    const unsigned short* vg0 = &Vg[(size_t)strow * SEQ + stcol];
    const unsigned short* vg1 = &Vg[(size_t)(strow + 32) * SEQ + stcol];

    short8 kr0 = *(const short8*)&kg0[0];
    short8 kr1 = *(const short8*)&kg1[0];
    short8 vr0 = *(const short8*)&vg0[0];
    short8 vr1 = *(const short8*)&vg1[0];

    floatx4 oacc[2][4];
    float lp[8];
#pragma unroll
    for (int mi = 0; mi < 2; ++mi)
#pragma unroll
        for (int n = 0; n < 4; ++n) oacc[mi][n] = (floatx4){0.f, 0.f, 0.f, 0.f};
#pragma unroll
    for (int r = 0; r < 8; ++r) lp[r] = 0.f;

    const int diag_kt = qt * QTILE + (wave >> 1) * 64;   // the only tile containing this wave's diagonal

    for (int kt = 0; kt < SEQ; kt += 64) {
        __syncthreads();
        *(short8*)&Ks[strow][stcol]      = kr0;
        *(short8*)&Ks[strow + 32][stcol] = kr1;
        *(short8*)&Vt[strow][stcol]      = vr0;
        *(short8*)&Vt[strow + 32][stcol] = vr1;
        __syncthreads();

        const int ktn = (kt + 64 < SEQ) ? kt + 64 : 0;
        kr0 = *(const short8*)&kg0[(size_t)ktn * DK];
        kr1 = *(const short8*)&kg1[(size_t)ktn * DK];
        vr0 = *(const short8*)&vg0[ktn];
        vr1 = *(const short8*)&vg1[ktn];

        // ---- S = Q K^T : 16 MFMAs, 8 K-frag reads (reused across 2 m-tiles) ----
        floatx4 s[2][4];
#pragma unroll
        for (int n = 0; n < 4; ++n) {
            const short8 kf0 = *(short8*)&Ks[n * 16 + lcol][quad * 8];
            const short8 kf1 = *(short8*)&Ks[n * 16 + lcol][32 + quad * 8];
#pragma unroll
            for (int mi = 0; mi < 2; ++mi) {
                floatx4 a = (floatx4){0.f, 0.f, 0.f, 0.f};
                a = __builtin_amdgcn_mfma_f32_16x16x32_bf16(qf[mi][0], kf0, a, 0, 0, 0);
                a = __builtin_amdgcn_mfma_f32_16x16x32_bf16(qf[mi][1], kf1, a, 0, 0, 0);
                s[mi][n] = a;
            }
        }

        // ---- diagonal mask: wave-uniform branch, 1 of 32 tiles ----
        if (kt == diag_kt) {
#pragma unroll
            for (int mi = 0; mi < 2; ++mi)
#pragma unroll
                for (int n = 0; n < 4; ++n) {
                    const int kg = kt + n * 16 + lcol;
                    const int qg = qt * QTILE + wq0 + mi * 16 + quad * 4;
#pragma unroll
                    for (int r = 0; r < 4; ++r)
                        if (kg == qg + r) s[mi][n][r] = -1e30f;
                }
        }

        // ---- P = exp2(S) (log2e folded into Q), row-sum partials, spill to LDS ----
#pragma unroll
        for (int mi = 0; mi < 2; ++mi)
#pragma unroll
            for (int n = 0; n < 4; ++n)
#pragma unroll
                for (int r = 0; r < 4; ++r) {
                    const float p = exp2f(s[mi][n][r]);
                    lp[mi * 4 + r] += p;
                    Ps[wq0 + mi * 16 + quad * 4 + r][n * 16 + lcol] = f2bf_fast(p);
                }
        // Ps is wave-local -> no barrier

        // ---- O += P V : 16 MFMAs, 8 V-frag reads ----
        short8 pf[2][2];
#pragma unroll
        for (int mi = 0; mi < 2; ++mi)
#pragma unroll
            for (int hf = 0; hf < 2; ++hf)
                pf[mi][hf] = *(short8*)&Ps[wq0 + mi * 16 + lcol][hf * 32 + quad * 8];
#pragma unroll
        for (int n = 0; n < 4; ++n) {
            const short8 vf0 = *(short8*)&Vt[n * 16 + lcol][quad * 8];
            const short8 vf1 = *(short8*)&Vt[n * 16 + lcol][32 + quad * 8];
#pragma unroll
            for (int mi = 0; mi < 2; ++mi) {
                oacc[mi][n] = __builtin_amdgcn_mfma_f32_16x16x32_bf16(pf[mi][0], vf0, oacc[mi][n], 0, 0, 0);
                oacc[mi][n] = __builtin_amdgcn_mfma_f32_16x16x32_bf16(pf[mi][1], vf1, oacc[mi][n], 0, 0, 0);
            }
        }
    }

    // ---- final row-sum reduction across the 16 lanes of each quad ----
#pragma unroll
    for (int r = 0; r < 8; ++r)
#pragma unroll
        for (int off = 1; off <= 8; off <<= 1)
            lp[r] += __shfl_xor(lp[r], off, 64);

    unsigned short* obase = attnb + ((size_t)b * SEQ + (size_t)qt * QTILE) * D_MODEL + h * DK;
#pragma unroll
    for (int mi = 0; mi < 2; ++mi)
#pragma unroll
        for (int r = 0; r < 4; ++r) {
            const float inv = 1.0f / lp[mi * 4 + r];
            const int qrow = wq0 + mi * 16 + quad * 4 + r;
#pragma unroll
            for (int n = 0; n < 4; ++n)
                obase[(size_t)qrow * D_MODEL + n * 16 + lcol] = f2bf(oacc[mi][n][r] * inv);
        }
}

extern "C" void kernel_launch(void* const* d_in, const int* in_sizes, int n_in,
                              void* d_out, int out_size, void* d_ws, size_t ws_size,
                              hipStream_t stream) {
    const float* x     = (const float*)d_in[0];
    const float* w_qkv = (const float*)d_in[1];
    const float* w_out = (const float*)d_in[2];
    const float* b_out = (const float*)d_in[3];
    float* out = (float*)d_out;

    const int M = BATCH * SEQ;                                   // 4096
    const size_t X_ELEMS    = (size_t)M * D_MODEL;
    const size_t WQKV_ELEMS = (size_t)3 * D_MODEL * D_MODEL;
    const size_t WOUT_ELEMS = (size_t)D_MODEL * D_MODEL;
    const size_t QKV_ELEMS  = (size_t)M * 3 * D_MODEL;
    const size_t HEAD_ELEMS = (size_t)BATCH * NHEADS * SEQ * DK;

    unsigned short* xb    = (unsigned short*)d_ws;
    unsigned short* wqkvb = xb + X_ELEMS;
    unsigned short* woutb = wqkvb + WQKV_ELEMS;
    unsigned short* qkvb  = woutb + WOUT_ELEMS;
    unsigned short* Qb    = qkvb + QKV_ELEMS;
    unsigned short* Kb    = Qb + HEAD_ELEMS;
    unsigned short* Vtg   = Kb + HEAD_ELEMS;                     // [B,H,64,S]
    unsigned short* attnb = Vtg + HEAD_ELEMS;

    // 0) pack all inputs to bf16 (one launch)
    pack_all<<<(X8 + W8 + O8 + 255) / 256, 256, 0, stream>>>(x, w_qkv, w_out, xb, wqkvb, woutb);

    // 1) qkvb = xb @ wqkvb^T
    {
        dim3 grid(3 * D_MODEL / 128, M / 128);
        gemm_bf16<unsigned short><<<grid, 256, 0, stream>>>(xb, wqkvb, nullptr, qkvb,
                                                            M, 3 * D_MODEL, D_MODEL);
    }
    // 2) RoPE pack + V transpose (one launch)
    {
        dim3 grid(SEQ / 64, NHEADS, BATCH);
        rope_vtrans<<<grid, 256, 0, stream>>>(qkvb, Qb, Kb, Vtg);
    }
    // 3) flash attention (128-query tiles)
    {
        dim3 grid(SEQ / QTILE, NHEADS, BATCH);
        flash_attn<<<grid, 256, 0, stream>>>(Qb, Kb, Vtg, attnb);
    }
    // 4) out = attnb @ woutb^T + b_out
    {
        dim3 grid(D_MODEL / 128, M / 128);
        gemm_bf16<float><<<grid, 256, 0, stream>>>(attnb, woutb, b_out, out,
                                                   M, D_MODEL, D_MODEL);
    }
}

// Round 6
// 227.068 us; speedup vs baseline: 24.9660x; 1.0301x over previous
//
#include <hip/hip_runtime.h>
#include <hip/hip_bf16.h>
#include <math.h>

#define D_MODEL 1024
#define NHEADS  16
#define DK      64
#define SEQ     2048
#define BATCH   2
#define QTILE   64

typedef __attribute__((ext_vector_type(8))) short  short8;
typedef __attribute__((ext_vector_type(8))) unsigned short ushort8;
typedef __attribute__((ext_vector_type(4))) float  floatx4;

__device__ __forceinline__ unsigned short f2bf(float f) {      // RNE
    union { float f; unsigned int u; } v; v.f = f;
    unsigned int u = v.u;
    return (unsigned short)((u + 0x7FFFu + ((u >> 16) & 1u)) >> 16);
}
__device__ __forceinline__ float bf2f(unsigned short u) {
    union { unsigned int u; float f; } v; v.u = ((unsigned int)u) << 16;
    return v.f;
}
// pack two floats -> packed bf16 (round-half-up; bias cancels in softmax ratio)
__device__ __forceinline__ unsigned int pack2bf(float a, float b) {
    union { float f; unsigned int u; } x, y; x.f = a; y.f = b;
    return ((x.u + 0x8000u) >> 16) | ((y.u + 0x8000u) & 0xFFFF0000u);
}

// async global->LDS, 16B per lane. LDS dest = wave-uniform base + lane*16.
__device__ __forceinline__ void gload_lds16(const unsigned short* g, unsigned short* l) {
    __builtin_amdgcn_global_load_lds((__attribute__((address_space(1))) const void*)g,
                                     (__attribute__((address_space(3))) void*)l,
                                     16, 0, 0);
}

// ---------------- fused fp32 -> bf16 pack of x, w_qkv, w_out ----------------
#define X8 ((BATCH * SEQ * D_MODEL) / 8)
#define W8 ((3 * D_MODEL * D_MODEL) / 8)
#define O8 ((D_MODEL * D_MODEL) / 8)
__global__ __launch_bounds__(256) void pack_all(const float* __restrict__ x,
                                                const float* __restrict__ wq,
                                                const float* __restrict__ wo,
                                                unsigned short* __restrict__ xb,
                                                unsigned short* __restrict__ wqb,
                                                unsigned short* __restrict__ wob) {
    const int t = blockIdx.x * blockDim.x + threadIdx.x;
    const float* src; unsigned short* dst; int idx;
    if (t < X8)           { src = x;  dst = xb;  idx = t; }
    else if (t < X8 + W8) { src = wq; dst = wqb; idx = t - X8; }
    else if (t < X8 + W8 + O8) { src = wo; dst = wob; idx = t - X8 - W8; }
    else return;
    const float4 a = ((const float4*)src)[2 * idx];
    const float4 b = ((const float4*)src)[2 * idx + 1];
    short8 o;
    o[0] = (short)f2bf(a.x); o[1] = (short)f2bf(a.y);
    o[2] = (short)f2bf(a.z); o[3] = (short)f2bf(a.w);
    o[4] = (short)f2bf(b.x); o[5] = (short)f2bf(b.y);
    o[6] = (short)f2bf(b.z); o[7] = (short)f2bf(b.w);
    ((short8*)dst)[idx] = o;
}

// ---------------- bf16 MFMA GEMM (m97 structure): C = A @ B^T (+bias) ----------------
// TM x 128 tile, BK=32, 256 threads = 4 waves (2x2), global_load_lds staging.
template <int TM, typename OUT_T>
__global__ __launch_bounds__(256) void gemm_bf16(const unsigned short* __restrict__ A,
                                                 const unsigned short* __restrict__ B,
                                                 const float* __restrict__ bias,
                                                 OUT_T* __restrict__ C,
                                                 int M, int N, int K) {
    constexpr int NAF = TM / 32;               // A-frags per wave
    __shared__ __align__(16) unsigned short As[TM][32];
    __shared__ __align__(16) unsigned short Bs[128][32];

    const int tid  = threadIdx.x;
    const int wave = tid >> 6;
    const int lane = tid & 63;
    const int quad = lane >> 4;
    const int lcol = lane & 15;
    const int wr   = (wave >> 1) * (TM / 2);
    const int wc   = (wave & 1) * 64;
    const int tm   = blockIdx.y * TM;
    const int tn   = blockIdx.x * 128;

    const int srowA = wave * (TM / 4) + (lane >> 2);
    const int srowB = wave * 32 + (lane >> 2);
    const int scol  = (lane & 3) * 8;
    const unsigned short* gB0 = B + (size_t)(tn + srowB) * K + scol;
    const unsigned short* gB1 = gB0 + (size_t)16 * K;
    unsigned short* lB0 = &Bs[wave * 32][0];
    unsigned short* lB1 = &Bs[wave * 32 + 16][0];

    floatx4 acc[NAF][4];
#pragma unroll
    for (int i = 0; i < NAF; ++i)
#pragma unroll
        for (int j = 0; j < 4; ++j) acc[i][j] = (floatx4){0.f, 0.f, 0.f, 0.f};

    for (int k0 = 0; k0 < K; k0 += 32) {
        __syncthreads();
#pragma unroll
        for (int u = 0; u < TM / 64; ++u)
            gload_lds16(A + (size_t)(tm + srowA + u * 16) * K + k0 + scol,
                        &As[wave * (TM / 4) + u * 16][0]);
        gload_lds16(gB0 + k0, lB0);
        gload_lds16(gB1 + k0, lB1);
        __syncthreads();

        short8 af[NAF], bf[4];
#pragma unroll
        for (int i = 0; i < NAF; ++i) af[i] = *(short8*)&As[wr + i * 16 + lcol][quad * 8];
#pragma unroll
        for (int j = 0; j < 4; ++j) bf[j] = *(short8*)&Bs[wc + j * 16 + lcol][quad * 8];
#pragma unroll
        for (int i = 0; i < NAF; ++i)
#pragma unroll
            for (int j = 0; j < 4; ++j)
                acc[i][j] = __builtin_amdgcn_mfma_f32_16x16x32_bf16(af[i], bf[j], acc[i][j], 0, 0, 0);
    }

#pragma unroll
    for (int i = 0; i < NAF; ++i) {
#pragma unroll
        for (int r = 0; r < 4; ++r) {
            const int row = tm + wr + i * 16 + quad * 4 + r;
#pragma unroll
            for (int j = 0; j < 4; ++j) {
                const int col = tn + wc + j * 16 + lcol;
                float v = acc[i][j][r];
                if (bias) v += bias[col];
                if constexpr (sizeof(OUT_T) == 2)
                    C[(size_t)row * N + col] = (OUT_T)f2bf(v);
                else
                    C[(size_t)row * N + col] = (OUT_T)v;
            }
        }
    }
}

// ---------------- fused RoPE pack (Q*0.125*log2e, K) + kappa-permuted V transpose ----
// kappa(t) = (t&15)*4 + (t>>4) within each 64-key tile; Vtg[B,H,64,S] stores V[t][d]
// at column kappa(t). flash's PV contracts over kappa consistently.
__global__ __launch_bounds__(256) void rope_vtrans(const unsigned short* __restrict__ qkvb,
                                                   unsigned short* __restrict__ Qb,
                                                   unsigned short* __restrict__ Kb,
                                                   unsigned short* __restrict__ Vtg) {
    const int st = blockIdx.x, h = blockIdx.y, b = blockIdx.z;
    const int tid = threadIdx.x;
    const int s0 = st * 64;

    // ---- RoPE on Q,K ----
    const int i  = tid & 31;
    const int r0 = tid >> 5;                   // 0..7
    const float inv_freq = exp2f(-(2.0f * (float)i / (float)DK) * log2f(50.0f));
    const float QSCALE = 0.125f * 1.44269504f; // 1/sqrt(dk) * log2(e)
#pragma unroll
    for (int pass = 0; pass < 8; ++pass) {
        const int s = s0 + r0 + pass * 8;
        const size_t in_base = ((size_t)(b * SEQ + s)) * (3 * D_MODEL) + h * DK + 2 * i;
        const float q0 = bf2f(qkvb[in_base]),           q1 = bf2f(qkvb[in_base + 1]);
        const float k0 = bf2f(qkvb[in_base + D_MODEL]), k1 = bf2f(qkvb[in_base + D_MODEL + 1]);
        float sn, cs;
        __sincosf((float)s * inv_freq, &sn, &cs);
        const size_t ob = (((size_t)(b * NHEADS + h)) * SEQ + s) * DK + 2 * i;
        const unsigned int qw = (unsigned int)f2bf((q0 * cs - q1 * sn) * QSCALE)
                              | ((unsigned int)f2bf((q1 * cs + q0 * sn) * QSCALE) << 16);
        const unsigned int kw = (unsigned int)f2bf(k0 * cs - k1 * sn)
                              | ((unsigned int)f2bf(k1 * cs + k0 * sn) << 16);
        *(unsigned int*)&Qb[ob] = qw;
        *(unsigned int*)&Kb[ob] = kw;
    }

    // ---- V transpose with kappa column permutation (applied on the LDS write side) ----
    __shared__ unsigned short Lt[64][65];
    const int r = tid >> 3;                    // 0..31 (= key row within tile)
    const int c = (tid & 7) * 8;
    const size_t in_row = ((size_t)(b * SEQ + s0 + r)) * (3 * D_MODEL) + 2 * D_MODEL + h * DK + c;
    const ushort8 v0 = *(const ushort8*)&qkvb[in_row];
    const ushort8 v1 = *(const ushort8*)&qkvb[in_row + (size_t)32 * (3 * D_MODEL)];
    const int kr0 = (r & 15) * 4 + (r >> 4);          // kappa(r)
    const int kr1 = ((r + 32) & 15) * 4 + ((r + 32) >> 4);
#pragma unroll
    for (int j = 0; j < 8; ++j) Lt[c + j][kr0] = v0[j];
#pragma unroll
    for (int j = 0; j < 8; ++j) Lt[c + j][kr1] = v1[j];
    __syncthreads();
    const size_t bh = (size_t)(b * NHEADS + h);
    ushort8 o0, o1;
#pragma unroll
    for (int j = 0; j < 8; ++j) { o0[j] = Lt[r][c + j]; o1[j] = Lt[r + 32][c + j]; }
    unsigned short* orow = Vtg + (bh * DK + r) * SEQ + s0 + c;   // here r = d-row
    *(ushort8*)orow = o0;
    *(ushort8*)(orow + (size_t)32 * SEQ) = o1;
}

// ---------------- flash attention: 64-q tile, deferred softmax, kappa-packed P ------
#define LDW 72

__global__ __launch_bounds__(256) void flash_attn(const unsigned short* __restrict__ Qb,
                                                  const unsigned short* __restrict__ Kb,
                                                  const unsigned short* __restrict__ Vtg,
                                                  unsigned short* __restrict__ attnb) {
    const int qt   = blockIdx.x;              // 0..31 (tiles of 64 queries)
    const int h    = blockIdx.y;
    const int b    = blockIdx.z;
    const int tid  = threadIdx.x;
    const int wave = tid >> 6;
    const int lane = tid & 63;
    const int quad = lane >> 4;
    const int lcol = lane & 15;
    const int m0   = wave * 16;

    __shared__ __align__(16) unsigned short Ks[64][LDW];
    __shared__ __align__(16) unsigned short Vt[64][LDW];    // [d][kappa]
    __shared__ __align__(16) unsigned short Ps[QTILE][LDW]; // [m][kappa]

    const size_t bh = (size_t)(b * NHEADS + h);
    const unsigned short* Qg = Qb + (bh * SEQ + (size_t)qt * QTILE) * DK;
    const unsigned short* Kg = Kb + bh * SEQ * DK;
    const unsigned short* Vg = Vtg + bh * (size_t)DK * SEQ;

    // Q fragments (one-time, from global)
    const unsigned short* qrow = Qg + (size_t)(m0 + lcol) * DK;
    const short8 qf0 = *(const short8*)&qrow[quad * 8];
    const short8 qf1 = *(const short8*)&qrow[32 + quad * 8];

    const int strow = tid >> 3;               // 0..31
    const int stcol = (tid & 7) * 8;
    const unsigned short* kg0 = &Kg[(size_t)strow * DK + stcol];
    const unsigned short* kg1 = &Kg[(size_t)(strow + 32) * DK + stcol];
    const unsigned short* vg0 = &Vg[(size_t)strow * SEQ + stcol];
    const unsigned short* vg1 = &Vg[(size_t)(strow + 32) * SEQ + stcol];

    short8 kr0 = *(const short8*)&kg0[0];
    short8 kr1 = *(const short8*)&kg1[0];
    short8 vr0 = *(const short8*)&vg0[0];
    short8 vr1 = *(const short8*)&vg1[0];

    floatx4 oacc[4];
    float lp[4];
#pragma unroll
    for (int n = 0; n < 4; ++n) oacc[n] = (floatx4){0.f, 0.f, 0.f, 0.f};
#pragma unroll
    for (int r = 0; r < 4; ++r) lp[r] = 0.f;

    const int diag_kt = (qt * QTILE) & ~63;   // tile containing this block's diagonal
    const int q_glob0 = qt * QTILE + m0 + quad * 4;

    for (int kt = 0; kt < SEQ; kt += 64) {
        __syncthreads();
        *(short8*)&Ks[strow][stcol]      = kr0;
        *(short8*)&Ks[strow + 32][stcol] = kr1;
        *(short8*)&Vt[strow][stcol]      = vr0;
        *(short8*)&Vt[strow + 32][stcol] = vr1;
        __syncthreads();

        const int ktn = (kt + 64 < SEQ) ? kt + 64 : 0;
        kr0 = *(const short8*)&kg0[(size_t)ktn * DK];
        kr1 = *(const short8*)&kg1[(size_t)ktn * DK];
        vr0 = *(const short8*)&vg0[ktn];
        vr1 = *(const short8*)&vg1[ktn];

        // ---- S = Q K^T ----
        floatx4 s[4];
#pragma unroll
        for (int n = 0; n < 4; ++n) {
            const short8 kf0 = *(short8*)&Ks[n * 16 + lcol][quad * 8];
            const short8 kf1 = *(short8*)&Ks[n * 16 + lcol][32 + quad * 8];
            floatx4 a = (floatx4){0.f, 0.f, 0.f, 0.f};
            a = __builtin_amdgcn_mfma_f32_16x16x32_bf16(qf0, kf0, a, 0, 0, 0);
            a = __builtin_amdgcn_mfma_f32_16x16x32_bf16(qf1, kf1, a, 0, 0, 0);
            s[n] = a;
        }

        // ---- diagonal mask (wave-uniform branch; 1 of 32 tiles) ----
        if (kt == diag_kt) {
#pragma unroll
            for (int n = 0; n < 4; ++n) {
                const int kg = kt + n * 16 + lcol;
#pragma unroll
                for (int r = 0; r < 4; ++r)
                    if (kg == q_glob0 + r) s[n][r] = -1e30f;
            }
        }

        // ---- P = exp2(S) (log2e folded into Q); row-sums; kappa-packed b64 spill ----
#pragma unroll
        for (int r = 0; r < 4; ++r) {
            const float p0 = exp2f(s[0][r]);
            const float p1 = exp2f(s[1][r]);
            const float p2 = exp2f(s[2][r]);
            const float p3 = exp2f(s[3][r]);
            lp[r] += (p0 + p1) + (p2 + p3);
            uint2 w;
            w.x = pack2bf(p0, p1);            // kappa = lcol*4 + {0,1}
            w.y = pack2bf(p2, p3);            // kappa = lcol*4 + {2,3}
            *(uint2*)&Ps[m0 + quad * 4 + r][lcol * 4] = w;
        }
        // Ps is wave-local -> no barrier

        // ---- O += P V (contracted over kappa) ----
        const short8 pf0 = *(short8*)&Ps[m0 + lcol][quad * 8];
        const short8 pf1 = *(short8*)&Ps[m0 + lcol][32 + quad * 8];
#pragma unroll
        for (int n = 0; n < 4; ++n) {
            const short8 vf0 = *(short8*)&Vt[n * 16 + lcol][quad * 8];
            const short8 vf1 = *(short8*)&Vt[n * 16 + lcol][32 + quad * 8];
            oacc[n] = __builtin_amdgcn_mfma_f32_16x16x32_bf16(pf0, vf0, oacc[n], 0, 0, 0);
            oacc[n] = __builtin_amdgcn_mfma_f32_16x16x32_bf16(pf1, vf1, oacc[n], 0, 0, 0);
        }
    }

    // ---- final row-sum reduction across the 16 lanes of each quad ----
#pragma unroll
    for (int r = 0; r < 4; ++r)
#pragma unroll
        for (int off = 1; off <= 8; off <<= 1)
            lp[r] += __shfl_xor(lp[r], off, 64);

    unsigned short* obase = attnb + ((size_t)b * SEQ + (size_t)qt * QTILE) * D_MODEL + h * DK;
#pragma unroll
    for (int r = 0; r < 4; ++r) {
        const float inv = 1.0f / lp[r];
        const int qrow2 = m0 + quad * 4 + r;
#pragma unroll
        for (int n = 0; n < 4; ++n)
            obase[(size_t)qrow2 * D_MODEL + n * 16 + lcol] = f2bf(oacc[n][r] * inv);
    }
}

extern "C" void kernel_launch(void* const* d_in, const int* in_sizes, int n_in,
                              void* d_out, int out_size, void* d_ws, size_t ws_size,
                              hipStream_t stream) {
    const float* x     = (const float*)d_in[0];
    const float* w_qkv = (const float*)d_in[1];
    const float* w_out = (const float*)d_in[2];
    const float* b_out = (const float*)d_in[3];
    float* out = (float*)d_out;

    const int M = BATCH * SEQ;                                   // 4096
    const size_t X_ELEMS    = (size_t)M * D_MODEL;
    const size_t WQKV_ELEMS = (size_t)3 * D_MODEL * D_MODEL;
    const size_t WOUT_ELEMS = (size_t)D_MODEL * D_MODEL;
    const size_t QKV_ELEMS  = (size_t)M * 3 * D_MODEL;
    const size_t HEAD_ELEMS = (size_t)BATCH * NHEADS * SEQ * DK;

    unsigned short* xb    = (unsigned short*)d_ws;
    unsigned short* wqkvb = xb + X_ELEMS;
    unsigned short* woutb = wqkvb + WQKV_ELEMS;
    unsigned short* qkvb  = woutb + WOUT_ELEMS;
    unsigned short* Qb    = qkvb + QKV_ELEMS;
    unsigned short* Kb    = Qb + HEAD_ELEMS;
    unsigned short* Vtg   = Kb + HEAD_ELEMS;                     // [B,H,64,S] (kappa cols)
    unsigned short* attnb = Vtg + HEAD_ELEMS;

    // 0) pack all inputs to bf16
    pack_all<<<(X8 + W8 + O8 + 255) / 256, 256, 0, stream>>>(x, w_qkv, w_out, xb, wqkvb, woutb);

    // 1) qkvb = xb @ wqkvb^T
    {
        dim3 grid(3 * D_MODEL / 128, M / 128);
        gemm_bf16<128, unsigned short><<<grid, 256, 0, stream>>>(xb, wqkvb, nullptr, qkvb,
                                                                 M, 3 * D_MODEL, D_MODEL);
    }
    // 2) RoPE pack + kappa-permuted V transpose
    {
        dim3 grid(SEQ / 64, NHEADS, BATCH);
        rope_vtrans<<<grid, 256, 0, stream>>>(qkvb, Qb, Kb, Vtg);
    }
    // 3) flash attention
    {
        dim3 grid(SEQ / QTILE, NHEADS, BATCH);
        flash_attn<<<grid, 256, 0, stream>>>(Qb, Kb, Vtg, attnb);
    }
    // 4) out = attnb @ woutb^T + b_out  (64x128 tiles -> 512 blocks, 2/CU)
    {
        dim3 grid(D_MODEL / 128, M / 64);
        gemm_bf16<64, float><<<grid, 256, 0, stream>>>(attnb, woutb, b_out, out,
                                                       M, D_MODEL, D_MODEL);
    }
}